// Round 4
// baseline (67.681 us; speedup 1.0000x reference)
//
#include <hip/hip_runtime.h>
#include <cstdint>
#include <cstddef>

typedef __attribute__((ext_vector_type(8))) short bf16x8;
typedef __attribute__((ext_vector_type(4))) float f32x4;
typedef __attribute__((ext_vector_type(2))) float f32x2;
typedef __attribute__((ext_vector_type(2))) unsigned int u32x2;

static constexpr int BROWS = 262144;
static constexpr int DIM   = 64;
static constexpr int NC    = 256;
static constexpr int OUTD  = 18;
static constexpr int BM    = 128;
static constexpr int NBLK  = 512;
static constexpr int NCHUNK = BROWS / BM / NBLK;  // 4

__device__ __forceinline__ unsigned cvt_pk_bf16(float a, float b) {
  unsigned r;
  asm("v_cvt_pk_bf16_f32 %0, %1, %2" : "=v"(r) : "v"(a), "v"(b));
  return r;
}

union U4 { unsigned u[4]; bf16x8 v; };

// pack 8 f32 -> 8 bf16 (RN), order-preserving
__device__ __forceinline__ bf16x8 pack8(const float* s) {
  U4 r;
#pragma unroll
  for (int p = 0; p < 4; ++p) r.u[p] = cvt_pk_bf16(s[2*p], s[2*p+1]);
  return r.v;
}

// split 8 f32 into bf16 hi + bf16 lo (lo = RN_bf16(x - hi))
__device__ __forceinline__ void split8(const float* s, bf16x8& hi, bf16x8& lo) {
  U4 h, l;
#pragma unroll
  for (int p = 0; p < 4; ++p) {
    float a = s[2*p], b = s[2*p+1];
    unsigned ph = cvt_pk_bf16(a, b);
    float ah = __uint_as_float(ph << 16);
    float bh = __uint_as_float(ph & 0xffff0000u);
    h.u[p] = ph;
    l.u[p] = cvt_pk_bf16(a - ah, b - bh);
  }
  hi = h.v; lo = l.v;
}

__global__ __launch_bounds__(512, 4) void rbf_fused(
    const float* __restrict__ x,  const float* __restrict__ Wr,
    const float* __restrict__ br, const float* __restrict__ Wl,
    const float* __restrict__ bl, float* __restrict__ out)
{
  // feat: bf16 bits, XOR-swizzled 16B chunks (verbatim R3 layout). 64 KB.
  __shared__ __align__(16) unsigned short feat[BM * NC];
  // wlds: W_lin rows 0..17 as bf16, 8-short-chunk XOR swizzle by (row&7). 9 KB.
  __shared__ __align__(16) unsigned short wlds[OUTD * NC];

  const int tid  = threadIdx.x;
  const int wav  = tid >> 6;      // 0..7
  const int lane = tid & 63;
  const int li   = lane & 15;
  const int g    = lane >> 4;

  const float S1 = 0.22507907903927651f;  // sqrt(2)/(2*pi): proj in revolutions
  const float SC = 0.08838834764831845f;  // sqrt(2/256)

  // ---- stage W_lin -> LDS (bf16, swizzled). 18 rows x 32 chunks of 8 shorts ----
  for (int idx = tid; idx < OUTD * 32; idx += 512) {
    const int r = idx >> 5, c = idx & 31;
    f32x4 v0 = *(const f32x4*)(Wl + r*NC + 8*c);
    f32x4 v1 = *(const f32x4*)(Wl + r*NC + 8*c + 4);
    float v[8];
    v[0]=v0.x; v[1]=v0.y; v[2]=v0.z; v[3]=v0.w;
    v[4]=v1.x; v[5]=v1.y; v[6]=v1.z; v[7]=v1.w;
    *(bf16x8*)(&wlds[r*NC + 8*(c ^ (r & 7))]) = pack8(v);
  }

  // ---- hoist A1 = (S1 * W_rbf)^T tile fragments, hi/lo.  nt = 2*wav + q ----
  bf16x8 a1h[2][2], a1l[2][2];
#pragma unroll
  for (int q = 0; q < 2; ++q) {
    const int n = 16 * (2*wav + q) + li;      // A1 row (component index)
#pragma unroll
    for (int kb = 0; kb < 2; ++kb) {
      float v[8];
#pragma unroll
      for (int j = 0; j < 8; ++j)
        v[j] = Wr[(size_t)(32*kb + 8*g + j) * NC + n] * S1;
      split8(v, a1h[q][kb], a1l[q][kb]);
    }
  }
  // b_rbf fragments: lane needs br[16*nt + 4g + j]
  f32x4 brf[2];
#pragma unroll
  for (int q = 0; q < 2; ++q)
    brf[q] = *(const f32x4*)(br + 16*(2*wav + q) + 4*g);

  const f32x4 bl0 = *(const f32x4*)(bl + 4*g);   // 4g+3 <= 15 < 18, safe
  const float bl16 = bl[16], bl17 = bl[17];
  // clamped row for the t=1 A2 tile: real rows 16,17 for li<2; any in-bounds row
  // otherwise (feeds only D rows >= 18, never stored).
  const int rowc = (li < 2) ? (16 + li) : li;

  asm volatile("s_waitcnt lgkmcnt(0)" ::: "memory");
  __builtin_amdgcn_s_barrier();
  asm volatile("" ::: "memory");

  const int cbase = blockIdx.x * NCHUNK;

  for (int i = 0; i < NCHUNK; ++i) {
    const float* xg = x + (size_t)(cbase + i) * BM * DIM;

    // ---- P1: proj^T tiles = A1(W^T) x B(x^T), 3-pass hi/lo; cos; feat -> LDS ----
#pragma unroll 2
    for (int rt = 0; rt < 8; ++rt) {
      const int rr = rt*16 + li;
      const int m  = rr & 7;
      const float* xp = xg + rr*64;
      float xv[16];
#pragma unroll
      for (int kb = 0; kb < 2; ++kb) {
        const int c0 = 8*kb + 2*g;
        f32x4 p0 = *(const f32x4*)(xp + 4*c0);
        f32x4 p1 = *(const f32x4*)(xp + 4*c0 + 4);
        xv[8*kb+0]=p0.x; xv[8*kb+1]=p0.y; xv[8*kb+2]=p0.z; xv[8*kb+3]=p0.w;
        xv[8*kb+4]=p1.x; xv[8*kb+5]=p1.y; xv[8*kb+6]=p1.z; xv[8*kb+7]=p1.w;
      }
      bf16x8 bh[2], blo_[2];
      split8(xv,     bh[0], blo_[0]);
      split8(xv + 8, bh[1], blo_[1]);

      f32x4 acc[2];
#pragma unroll
      for (int q = 0; q < 2; ++q) acc[q] = f32x4{0.f, 0.f, 0.f, 0.f};
#pragma unroll
      for (int kb = 0; kb < 2; ++kb) {
#pragma unroll
        for (int q = 0; q < 2; ++q) {
          acc[q] = __builtin_amdgcn_mfma_f32_16x16x32_bf16(a1h[q][kb], bh[kb],   acc[q], 0, 0, 0);
          acc[q] = __builtin_amdgcn_mfma_f32_16x16x32_bf16(a1l[q][kb], bh[kb],   acc[q], 0, 0, 0);
          acc[q] = __builtin_amdgcn_mfma_f32_16x16x32_bf16(a1h[q][kb], blo_[kb], acc[q], 0, 0, 0);
        }
      }
      // rev = proj(revolutions) + b_rbf; feat = cos(2*pi*rev)*SC, bf16, packed 8B write
#pragma unroll
      for (int q = 0; q < 2; ++q) {
        float c4[4];
#pragma unroll
        for (int j = 0; j < 4; ++j) {
          float rev = acc[q][j] + brf[q][j];
          float f   = rev - floorf(rev);                 // [0,1) revolutions
          c4[j] = __builtin_amdgcn_cosf(f) * SC;         // v_cos_f32 takes revolutions
        }
        u32x2 pk;
        pk.x = cvt_pk_bf16(c4[0], c4[1]);
        pk.y = cvt_pk_bf16(c4[2], c4[3]);
        const int nt   = 2*wav + q;
        const int slot = (2*nt + (g >> 1)) ^ m;          // 16B-chunk XOR swizzle
        *(u32x2*)(&feat[rr*256 + slot*8 + (g & 1)*4]) = pk;
      }
    }
    asm volatile("s_waitcnt lgkmcnt(0)" ::: "memory");
    __builtin_amdgcn_s_barrier();
    asm volatile("" ::: "memory");

    // ---- P2: out^T tiles = A2(W_lin from LDS) x B2(feat^T); one row-tile/wave ----
    {
      const int rr = wav*16 + li;               // rows 0..127, 16 per wave
      const int m  = rr & 7;                    // == li & 7
      f32x4 acc0 = f32x4{0.f,0.f,0.f,0.f};
      f32x4 acc1 = f32x4{0.f,0.f,0.f,0.f};
#pragma unroll
      for (int kb = 0; kb < 8; ++kb) {
        bf16x8 b2  = *(const bf16x8*)(&feat[rr*256 + (((4*kb + g) ^ m) * 8)]);
        bf16x8 a20 = *(const bf16x8*)(&wlds[li  *NC + 8*((4*kb + g) ^ (li   & 7))]);
        bf16x8 a21 = *(const bf16x8*)(&wlds[rowc*NC + 8*((4*kb + g) ^ (rowc & 7))]);
        acc0 = __builtin_amdgcn_mfma_f32_16x16x32_bf16(a20, b2, acc0, 0, 0, 0);
        acc1 = __builtin_amdgcn_mfma_f32_16x16x32_bf16(a21, b2, acc1, 0, 0, 0);
      }
      const size_t rg = (size_t)(cbase + i) * BM + rr;
      float* op = out + rg * OUTD;
      f32x2 s0; s0.x = acc0.x + bl0.x; s0.y = acc0.y + bl0.y;
      f32x2 s1; s1.x = acc0.z + bl0.z; s1.y = acc0.w + bl0.w;
      *(f32x2*)(op + 4*g)     = s0;   // o = 4g..4g+3 (all < 16)
      *(f32x2*)(op + 4*g + 2) = s1;
      if (g == 0) {                   // o = 16,17
        f32x2 s2; s2.x = acc1.x + bl16; s2.y = acc1.y + bl17;
        *(f32x2*)(op + 16) = s2;
      }
    }
    asm volatile("s_waitcnt lgkmcnt(0)" ::: "memory");
    __builtin_amdgcn_s_barrier();
    asm volatile("" ::: "memory");
  }
}

extern "C" void kernel_launch(void* const* d_in, const int* in_sizes, int n_in,
                              void* d_out, int out_size, void* d_ws, size_t ws_size,
                              hipStream_t stream) {
  (void)in_sizes; (void)n_in; (void)d_ws; (void)ws_size; (void)out_size;
  const float* x  = (const float*)d_in[0];
  const float* Wr = (const float*)d_in[1];
  const float* br = (const float*)d_in[2];
  const float* Wl = (const float*)d_in[3];
  const float* bl = (const float*)d_in[4];
  rbf_fused<<<NBLK, 512, 0, stream>>>(x, Wr, br, Wl, bl, (float*)d_out);
}

// Round 6
// 38.680 us; speedup vs baseline: 1.7497x; 1.7497x over previous
//
#include <hip/hip_runtime.h>
#include <cstdint>
#include <cstddef>

typedef __attribute__((ext_vector_type(8))) short bf16x8;
typedef __attribute__((ext_vector_type(4))) float f32x4;
typedef __attribute__((ext_vector_type(2))) float f32x2;
typedef __attribute__((ext_vector_type(2))) unsigned int u32x2;

static constexpr int BROWS = 262144;
static constexpr int DIM   = 64;
static constexpr int NC    = 256;
static constexpr int OUTD  = 18;
static constexpr int BM    = 64;     // rows per chunk
static constexpr int NBLK  = 512;
static constexpr int NCH   = BROWS / BM / NBLK;  // 8

__device__ __forceinline__ unsigned cvt_pk_bf16(float a, float b) {
  unsigned r;
  asm("v_cvt_pk_bf16_f32 %0, %1, %2" : "=v"(r) : "v"(a), "v"(b));
  return r;
}

union U4 { unsigned u[4]; bf16x8 v; };

// pack 8 f32 -> 8 bf16 (RN), order-preserving
__device__ __forceinline__ bf16x8 pack8(const float* s) {
  U4 r;
#pragma unroll
  for (int p = 0; p < 4; ++p) r.u[p] = cvt_pk_bf16(s[2*p], s[2*p+1]);
  return r.v;
}

// split 8 f32 into bf16 hi + bf16 lo (lo = RN_bf16(x - hi))
__device__ __forceinline__ void split8(const float* s, bf16x8& hi, bf16x8& lo) {
  U4 h, l;
#pragma unroll
  for (int p = 0; p < 4; ++p) {
    float a = s[2*p], b = s[2*p+1];
    unsigned ph = cvt_pk_bf16(a, b);
    float ah = __uint_as_float(ph << 16);
    float bh = __uint_as_float(ph & 0xffff0000u);
    h.u[p] = ph;
    l.u[p] = cvt_pk_bf16(a - ah, b - bh);
  }
  hi = h.v; lo = l.v;
}

__global__ __launch_bounds__(512, 4) void rbf_fused(
    const float* __restrict__ x,  const float* __restrict__ Wr,
    const float* __restrict__ br, const float* __restrict__ Wl,
    const float* __restrict__ bl, float* __restrict__ out)
{
  // x split once per chunk: hi/lo bf16, 16B-chunk XOR-swizzled by (row&7). 8 KB each.
  __shared__ __align__(16) unsigned short xhi[BM * DIM];
  __shared__ __align__(16) unsigned short xlo[BM * DIM];
  // feat: bf16 bits, XOR-swizzled 16B chunks (proven R3/R4 layout). 32 KB.
  __shared__ __align__(16) unsigned short feat[BM * NC];
  // wlds: W_lin rows 0..17 bf16 (no SC fold — R4 semantics). 9 KB.
  __shared__ __align__(16) unsigned short wlds[OUTD * NC];

  const int tid  = threadIdx.x;
  const int wav  = tid >> 6;      // 0..7
  const int lane = tid & 63;
  const int li   = lane & 15;
  const int g    = lane >> 4;

  const float S1 = 0.22507907903927651f;  // sqrt(2)/(2*pi): proj in revolutions
  const float SC = 0.08838834764831845f;  // sqrt(2/256), applied to feat (R4 semantics)

  // ---- stage W_lin -> LDS (bf16, swizzled). Verbatim R4. ----
  for (int idx = tid; idx < OUTD * 32; idx += 512) {
    const int r = idx >> 5, c = idx & 31;
    f32x4 v0 = *(const f32x4*)(Wl + r*NC + 8*c);
    f32x4 v1 = *(const f32x4*)(Wl + r*NC + 8*c + 4);
    float v[8];
    v[0]=v0.x; v[1]=v0.y; v[2]=v0.z; v[3]=v0.w;
    v[4]=v1.x; v[5]=v1.y; v[6]=v1.z; v[7]=v1.w;
    *(bf16x8*)(&wlds[r*NC + 8*(c ^ (r & 7))]) = pack8(v);
  }

  // ---- hoist A1 = (S1 * W_rbf)^T tile fragments, hi/lo.  nt = 2*wav + q. Verbatim R4. ----
  bf16x8 a1h[2][2], a1l[2][2];
#pragma unroll
  for (int q = 0; q < 2; ++q) {
    const int n = 16 * (2*wav + q) + li;      // component index
#pragma unroll
    for (int kb = 0; kb < 2; ++kb) {
      float v[8];
#pragma unroll
      for (int j = 0; j < 8; ++j)
        v[j] = Wr[(size_t)(32*kb + 8*g + j) * NC + n] * S1;
      split8(v, a1h[q][kb], a1l[q][kb]);
    }
  }
  f32x4 brf[2];
#pragma unroll
  for (int q = 0; q < 2; ++q)
    brf[q] = *(const f32x4*)(br + 16*(2*wav + q) + 4*g);

  const f32x4 bl0 = *(const f32x4*)(bl + 4*g);   // o = 4g..4g+3 <= 15 < 18
  const float bl16 = bl[16], bl17 = bl[17];
  const int rowc = (li < 2) ? (16 + li) : li;    // t=1 A2 row (dummy rows harmless)

  asm volatile("s_waitcnt lgkmcnt(0)" ::: "memory");
  __builtin_amdgcn_s_barrier();
  asm volatile("" ::: "memory");

  const int sr = tid >> 3;   // staging row 0..63
  const int sc = tid & 7;    // staging 16B chunk 0..7
  const int cbase = blockIdx.x * NCH;

  for (int i = 0; i < NCH; ++i) {
    const int R = (cbase + i) * BM;

    // ---- stage: load x once, split once -> xhi/xlo LDS ----
    {
      const float* xp = x + ((size_t)R + sr) * DIM + sc*8;
      f32x4 pv0 = *(const f32x4*)(xp);
      f32x4 pv1 = *(const f32x4*)(xp + 4);
      float v[8];
      v[0]=pv0.x; v[1]=pv0.y; v[2]=pv0.z; v[3]=pv0.w;
      v[4]=pv1.x; v[5]=pv1.y; v[6]=pv1.z; v[7]=pv1.w;
      bf16x8 h, l;
      split8(v, h, l);
      const int off = sr*DIM + 8*(sc ^ (sr & 7));
      *(bf16x8*)(&xhi[off]) = h;
      *(bf16x8*)(&xlo[off]) = l;
    }
    asm volatile("s_waitcnt lgkmcnt(0)" ::: "memory");
    __builtin_amdgcn_s_barrier();
    asm volatile("" ::: "memory");

    // ---- P1: proj^T tiles = A1 x B(x^T from LDS), 3-pass hi/lo; cos; feat -> LDS ----
#pragma unroll 2
    for (int rt = 0; rt < 4; ++rt) {
      const int rr = rt*16 + li;
      const int m  = li & 7;                   // == rr&7
      bf16x8 bh[2], blo_[2];
#pragma unroll
      for (int kb = 0; kb < 2; ++kb) {
        const int slot = 8*((4*kb + g) ^ m);
        bh[kb]   = *(const bf16x8*)(&xhi[rr*DIM + slot]);
        blo_[kb] = *(const bf16x8*)(&xlo[rr*DIM + slot]);
      }
      f32x4 acc[2];
#pragma unroll
      for (int q = 0; q < 2; ++q) acc[q] = f32x4{0.f, 0.f, 0.f, 0.f};
#pragma unroll
      for (int kb = 0; kb < 2; ++kb) {
#pragma unroll
        for (int q = 0; q < 2; ++q) {
          acc[q] = __builtin_amdgcn_mfma_f32_16x16x32_bf16(a1h[q][kb], bh[kb],   acc[q], 0, 0, 0);
          acc[q] = __builtin_amdgcn_mfma_f32_16x16x32_bf16(a1l[q][kb], bh[kb],   acc[q], 0, 0, 0);
          acc[q] = __builtin_amdgcn_mfma_f32_16x16x32_bf16(a1h[q][kb], blo_[kb], acc[q], 0, 0, 0);
        }
      }
      // rev = proj + b_rbf; feat = cos(2*pi*rev)*SC, bf16, packed 8B write. Verbatim R4.
#pragma unroll
      for (int q = 0; q < 2; ++q) {
        float c4[4];
#pragma unroll
        for (int j = 0; j < 4; ++j) {
          float rev = acc[q][j] + brf[q][j];
          float f   = rev - floorf(rev);                 // [0,1) revolutions
          c4[j] = __builtin_amdgcn_cosf(f) * SC;
        }
        u32x2 pk;
        pk.x = cvt_pk_bf16(c4[0], c4[1]);
        pk.y = cvt_pk_bf16(c4[2], c4[3]);
        const int nt   = 2*wav + q;
        const int slot = (2*nt + (g >> 1)) ^ m;          // 16B-chunk XOR swizzle
        *(u32x2*)(&feat[rr*256 + slot*8 + (g & 1)*4]) = pk;
      }
    }
    asm volatile("s_waitcnt lgkmcnt(0)" ::: "memory");
    __builtin_amdgcn_s_barrier();
    asm volatile("" ::: "memory");

    // ---- P2: verbatim R4 body, gated to waves 0..3 (rows 0..63) ----
    if (wav < 4) {
      const int rr = wav*16 + li;               // rows 0..63, 16 per wave
      const int m  = li & 7;                    // == rr&7
      f32x4 acc0 = f32x4{0.f,0.f,0.f,0.f};
      f32x4 acc1 = f32x4{0.f,0.f,0.f,0.f};
#pragma unroll
      for (int kb = 0; kb < 8; ++kb) {
        bf16x8 b2  = *(const bf16x8*)(&feat[rr*256 + (((4*kb + g) ^ m) * 8)]);
        bf16x8 a20 = *(const bf16x8*)(&wlds[li  *NC + 8*((4*kb + g) ^ (li   & 7))]);
        bf16x8 a21 = *(const bf16x8*)(&wlds[rowc*NC + 8*((4*kb + g) ^ (rowc & 7))]);
        acc0 = __builtin_amdgcn_mfma_f32_16x16x32_bf16(a20, b2, acc0, 0, 0, 0);
        acc1 = __builtin_amdgcn_mfma_f32_16x16x32_bf16(a21, b2, acc1, 0, 0, 0);
      }
      float* op = out + (size_t)(R + rr) * OUTD;
      f32x2 s0; s0.x = acc0.x + bl0.x; s0.y = acc0.y + bl0.y;
      f32x2 s1; s1.x = acc0.z + bl0.z; s1.y = acc0.w + bl0.w;
      *(f32x2*)(op + 4*g)     = s0;   // o = 4g..4g+3 (all < 16)
      *(f32x2*)(op + 4*g + 2) = s1;
      if (g == 0) {                   // o = 16,17
        f32x2 s2; s2.x = acc1.x + bl16; s2.y = acc1.y + bl17;
        *(f32x2*)(op + 16) = s2;
      }
    }
    asm volatile("s_waitcnt lgkmcnt(0)" ::: "memory");
    __builtin_amdgcn_s_barrier();
    asm volatile("" ::: "memory");
  }
}

extern "C" void kernel_launch(void* const* d_in, const int* in_sizes, int n_in,
                              void* d_out, int out_size, void* d_ws, size_t ws_size,
                              hipStream_t stream) {
  (void)in_sizes; (void)n_in; (void)d_ws; (void)ws_size; (void)out_size;
  const float* x  = (const float*)d_in[0];
  const float* Wr = (const float*)d_in[1];
  const float* br = (const float*)d_in[2];
  const float* Wl = (const float*)d_in[3];
  const float* bl = (const float*)d_in[4];
  rbf_fused<<<NBLK, 512, 0, stream>>>(x, Wr, br, Wl, bl, (float*)d_out);
}